// Round 6
// baseline (431.877 us; speedup 1.0000x reference)
//
#include <hip/hip_runtime.h>
#include <hip/hip_bf16.h>

#define NNODES 100000
#define NEDGES 1600000
#define IN_CH 128
#define HID 64
#define NC 40
#define NPAD 100352   // NNODES padded to multiple of 256
#define NRANGE 8
#define RANGE_SZ 12500   // NNODES / 8
#define CHUNK 4096
#define NCHUNK 391       // 391*4096 = 1601536 >= NEDGES

typedef unsigned short ushort_t;
typedef unsigned int uint_t;
typedef __attribute__((ext_vector_type(8))) short short8;
typedef __attribute__((ext_vector_type(4))) float floatx4;

__device__ __forceinline__ float bf2f(ushort_t u) {
    union { unsigned int i; float f; } t;
    t.i = ((unsigned int)u) << 16;
    return t.f;
}
__device__ __forceinline__ ushort_t f2bf(float f) {
    union { float ff; unsigned int i; } t;
    t.ff = f;
    unsigned int r = t.i + 0x7fff + ((t.i >> 16) & 1);  // RNE
    return (ushort_t)(r >> 16);
}
// unpack packed bf16x2 (low = even feature, high = odd feature)
__device__ __forceinline__ float2 unpk(uint_t p) {
    union { unsigned int i; float f; } a, b;
    a.i = p << 16;
    b.i = p & 0xffff0000u;
    return make_float2(a.f, b.f);
}

// ---- CSR build: histogram of dst ----
__global__ void k_hist(const int* __restrict__ dsts, int* __restrict__ counts, int e) {
    int i = blockIdx.x * blockDim.x + threadIdx.x;
    if (i < e) atomicAdd(&counts[__builtin_nontemporal_load(dsts + i)], 1);
}

// block-local exclusive scan (256 wide), block totals to partials
__global__ __launch_bounds__(256) void k_scan1(const int* __restrict__ counts,
                                               int* __restrict__ excl, int* __restrict__ partials, int n) {
    __shared__ int s[256];
    int t = threadIdx.x;
    int i = blockIdx.x * 256 + t;
    int c = (i < n) ? counts[i] : 0;
    s[t] = c;
    __syncthreads();
    for (int off = 1; off < 256; off <<= 1) {
        int v = (t >= off) ? s[t - off] : 0;
        __syncthreads();
        s[t] += v;
        __syncthreads();
    }
    if (i < n) excl[i] = s[t] - c;
    if (t == 255) partials[blockIdx.x] = s[t];
}

// scan the 391 block totals (single block)
__global__ __launch_bounds__(512) void k_scan2(int* __restrict__ partials, int nb) {
    __shared__ int s[512];
    int t = threadIdx.x;
    int c = (t < nb) ? partials[t] : 0;
    s[t] = c;
    __syncthreads();
    for (int off = 1; off < 512; off <<= 1) {
        int v = (t >= off) ? s[t - off] : 0;
        __syncthreads();
        s[t] += v;
        __syncthreads();
    }
    if (t < nb) partials[t] = s[t] - c;  // exclusive
}

// fixup: final row_start, cursor copy, dinv from counts (+1 self-loop)
__global__ void k_scan3(const int* __restrict__ counts, const int* __restrict__ partials,
                        int* __restrict__ row_start, int* __restrict__ cursor,
                        float* __restrict__ dinv, int n, int e) {
    int i = blockIdx.x * blockDim.x + threadIdx.x;
    if (i < n) {
        int rs = row_start[i] + partials[i >> 8];
        row_start[i] = rs;
        cursor[i] = rs;
        dinv[i] = rsqrtf((float)counts[i] + 1.0f);
        if (i == 0) row_start[n] = e;
    }
}

// ---- range-partitioned rank-scatter; nt reads protect the L2 write window ----
__global__ __launch_bounds__(256) void k_scatter(
    const int* __restrict__ srcs, const int* __restrict__ dsts,
    const float* __restrict__ dinv,
    int* __restrict__ cursor, int2* __restrict__ ew, int e)
{
    int range = blockIdx.x & (NRANGE - 1);
    int chunk = blockIdx.x >> 3;
    int lo = range * RANGE_SZ;
    int hi = lo + RANGE_SZ;
    int begin = chunk * CHUNK;
    int end = begin + CHUNK;
    if (end > e) end = e;
    for (int i = begin + threadIdx.x; i < end; i += 256) {
        int d = __builtin_nontemporal_load(dsts + i);  // streaming: don't evict write window
        if (d >= lo && d < hi) {
            int s = srcs[i];
            float w = dinv[s] * dinv[d];
            int pos = atomicAdd(&cursor[d], 1);
            ew[pos] = make_int2(s, __float_as_int(w));
        }
    }
}

// ---- pre-swizzle W1 (f32) into bf16 B-fragment order ----
__global__ void k_prepw(const float* __restrict__ W1, ushort_t* __restrict__ Wp) {
    int i = blockIdx.x * 256 + threadIdx.x;
    if (i >= IN_CH * HID) return;
    int j = i & 7;
    int m = (i >> 3) & 15;
    int ct = (i >> 7) & 3;
    int quad = (i >> 9) & 3;
    int kc = i >> 11;
    int k = kc * 32 + quad * 8 + j;
    int c = ct * 16 + m;
    Wp[i] = f2bf(W1[k * HID + c]);
}

// ---- GEMM1: hw1 = bf16(x @ W1) via MFMA ----
__global__ __launch_bounds__(256) void k_gemm1(
    const float* __restrict__ x, const ushort_t* __restrict__ Wp,
    ushort_t* __restrict__ hw1, int n)
{
    int wave = threadIdx.x >> 6;
    int lane = threadIdx.x & 63;
    int m = lane & 15;
    int quad = lane >> 4;
    int row = blockIdx.x * 64 + wave * 16 + m;
    int rowc = row < n ? row : (n - 1);
    const float* xr = x + (size_t)rowc * IN_CH + quad * 8;

    floatx4 acc[4];
#pragma unroll
    for (int ct = 0; ct < 4; ++ct) acc[ct] = (floatx4){0.f, 0.f, 0.f, 0.f};

#pragma unroll
    for (int kc = 0; kc < 4; ++kc) {
        float4 xa = *(const float4*)(xr + kc * 32);
        float4 xb = *(const float4*)(xr + kc * 32 + 4);
        short8 a;
        a[0] = (short)f2bf(xa.x); a[1] = (short)f2bf(xa.y);
        a[2] = (short)f2bf(xa.z); a[3] = (short)f2bf(xa.w);
        a[4] = (short)f2bf(xb.x); a[5] = (short)f2bf(xb.y);
        a[6] = (short)f2bf(xb.z); a[7] = (short)f2bf(xb.w);
#pragma unroll
        for (int ct = 0; ct < 4; ++ct) {
            short8 b = *(const short8*)(Wp + ((((kc * 4 + quad) * 4 + ct) * 16 + m) << 3));
            acc[ct] = __builtin_amdgcn_mfma_f32_16x16x32_bf16(a, b, acc[ct], 0, 0, 0);
        }
    }
    int r0 = blockIdx.x * 64 + wave * 16 + quad * 4;
#pragma unroll
    for (int r = 0; r < 4; ++r) {
        int rr = r0 + r;
        if (rr < n) {
            ushort_t* o = hw1 + (size_t)rr * HID + m;
#pragma unroll
            for (int ct = 0; ct < 4; ++ct) o[ct * 16] = f2bf(acc[ct][r]);
        }
    }
}

// ---- agg1: one wave per node, half-wave = edge, lane = feature PAIR (ushort2) ----
// half 0 (lanes 0-31) and half 1 (lanes 32-63) process different edges;
// each gather instr moves 2 edges x 128 B; combine halves via shfl_xor 32.
__global__ __launch_bounds__(256) void k_agg1(
    const int* __restrict__ row_start, const int2* __restrict__ ew,
    const float* __restrict__ dinv, const uint_t* __restrict__ hw1u,
    const float* __restrict__ b1, float* __restrict__ h, int n)
{
    int node = blockIdx.x * 4 + (threadIdx.x >> 6);
    if (node >= n) return;
    int lane = threadIdx.x & 63;
    int half = lane >> 5;
    int l = lane & 31;           // feature pair index: features 2l, 2l+1
    int rs = row_start[node];
    int re = row_start[node + 1];
    float di = dinv[node];

    float2 acc0 = make_float2(0.f, 0.f), acc1 = make_float2(0.f, 0.f);
    if (half == 0) {  // self-loop only in half 0
        float2 v = unpk(hw1u[node * 32 + l]);
        float sl = di * di;
        acc0.x = v.x * sl; acc0.y = v.y * sl;
    }
    int kb = rs;
    for (; kb + 7 < re; kb += 8) {
        int base = kb + half * 4;  // half0: kb..kb+3, half1: kb+4..kb+7
        int2 e0 = ew[base], e1 = ew[base + 1], e2 = ew[base + 2], e3 = ew[base + 3];
        uint_t p0 = hw1u[e0.x * 32 + l];
        uint_t p1 = hw1u[e1.x * 32 + l];
        uint_t p2 = hw1u[e2.x * 32 + l];
        uint_t p3 = hw1u[e3.x * 32 + l];
        float w0 = __int_as_float(e0.y), w1 = __int_as_float(e1.y);
        float w2 = __int_as_float(e2.y), w3 = __int_as_float(e3.y);
        float2 v0 = unpk(p0), v1 = unpk(p1), v2 = unpk(p2), v3 = unpk(p3);
        acc0.x += v0.x * w0; acc0.y += v0.y * w0;
        acc1.x += v1.x * w1; acc1.y += v1.y * w1;
        acc0.x += v2.x * w2; acc0.y += v2.y * w2;
        acc1.x += v3.x * w3; acc1.y += v3.y * w3;
    }
    for (int k = kb + half; k < re; k += 2) {  // remainder: alternate halves
        int2 e0 = ew[k];
        float2 v = unpk(hw1u[e0.x * 32 + l]);
        float w = __int_as_float(e0.y);
        acc1.x += v.x * w; acc1.y += v.y * w;
    }
    float ax = (acc0.x + acc1.x), ay = (acc0.y + acc1.y);
    ax += __shfl_xor(ax, 32);
    ay += __shfl_xor(ay, 32);
    if (half == 0) {
        float2 b = ((const float2*)b1)[l];
        float vx = ax + b.x, vy = ay + b.y;
        vx = vx > 0.f ? vx : 0.f;
        vy = vy > 0.f ? vy : 0.f;
        ((float2*)h)[node * 32 + l] = make_float2(vx, vy);  // 256 B coalesced
    }
}

// ---- GEMM2: hw2 = bf16(h @ W2) (f32 vector ALU, W2 in LDS) ----
__global__ __launch_bounds__(256) void k_gemm2(
    const float* __restrict__ h, const float* __restrict__ W2,
    ushort_t* __restrict__ hw2, int n)
{
    __shared__ float wsm[HID * NC];  // 10 KB
    for (int i = threadIdx.x; i < HID * NC; i += 256) wsm[i] = W2[i];
    __syncthreads();
    int row = blockIdx.x * 256 + threadIdx.x;
    if (row >= n) return;
    const float4* hr = (const float4*)(h + (size_t)row * HID);
    float acc[NC];
#pragma unroll
    for (int c = 0; c < NC; ++c) acc[c] = 0.f;
#pragma unroll 4
    for (int k4 = 0; k4 < HID / 4; ++k4) {
        float4 hv = hr[k4];
        const float* w0 = wsm + (k4 * 4) * NC;
#pragma unroll
        for (int c = 0; c < NC; ++c)
            acc[c] += hv.x * w0[c] + hv.y * w0[c + NC] + hv.z * w0[c + 2 * NC] + hv.w * w0[c + 3 * NC];
    }
    unsigned int* o = (unsigned int*)(hw2 + (size_t)row * NC);
#pragma unroll
    for (int c2 = 0; c2 < NC / 2; ++c2)
        o[c2] = (unsigned int)f2bf(acc[2 * c2]) | ((unsigned int)f2bf(acc[2 * c2 + 1]) << 16);
}

// ---- agg2: one wave per node, half-wave = edge, lanes 0..19 of each half = class pairs ----
__global__ __launch_bounds__(256) void k_agg2(
    const int* __restrict__ row_start, const int2* __restrict__ ew,
    const float* __restrict__ dinv, const uint_t* __restrict__ hw2u,
    const float* __restrict__ b2, float* __restrict__ out, int n)
{
    int node = blockIdx.x * 4 + (threadIdx.x >> 6);
    if (node >= n) return;
    int lane = threadIdx.x & 63;
    int half = lane >> 5;
    int l = lane & 31;
    int li = l < 20 ? l : 0;  // clamp idle lanes to a valid address
    int rs = row_start[node];
    int re = row_start[node + 1];
    float di = dinv[node];

    float2 acc0 = make_float2(0.f, 0.f), acc1 = make_float2(0.f, 0.f);
    if (half == 0) {
        float2 v = unpk(hw2u[node * 20 + li]);
        float sl = di * di;
        acc0.x = v.x * sl; acc0.y = v.y * sl;
    }
    int kb = rs;
    for (; kb + 7 < re; kb += 8) {
        int base = kb + half * 4;
        int2 e0 = ew[base], e1 = ew[base + 1], e2 = ew[base + 2], e3 = ew[base + 3];
        uint_t p0 = hw2u[e0.x * 20 + li];
        uint_t p1 = hw2u[e1.x * 20 + li];
        uint_t p2 = hw2u[e2.x * 20 + li];
        uint_t p3 = hw2u[e3.x * 20 + li];
        float w0 = __int_as_float(e0.y), w1 = __int_as_float(e1.y);
        float w2 = __int_as_float(e2.y), w3 = __int_as_float(e3.y);
        float2 v0 = unpk(p0), v1 = unpk(p1), v2 = unpk(p2), v3 = unpk(p3);
        acc0.x += v0.x * w0; acc0.y += v0.y * w0;
        acc1.x += v1.x * w1; acc1.y += v1.y * w1;
        acc0.x += v2.x * w2; acc0.y += v2.y * w2;
        acc1.x += v3.x * w3; acc1.y += v3.y * w3;
    }
    for (int k = kb + half; k < re; k += 2) {
        int2 e0 = ew[k];
        float2 v = unpk(hw2u[e0.x * 20 + li]);
        float w = __int_as_float(e0.y);
        acc1.x += v.x * w; acc1.y += v.y * w;
    }
    float ax = (acc0.x + acc1.x), ay = (acc0.y + acc1.y);
    ax += __shfl_xor(ax, 32);
    ay += __shfl_xor(ay, 32);
    if (half == 0 && l < 20) {
        float2 b = ((const float2*)b2)[l];
        ((float2*)out)[node * 20 + l] = make_float2(ax + b.x, ay + b.y);  // 160 B coalesced
    }
}

extern "C" void kernel_launch(void* const* d_in, const int* in_sizes, int n_in,
                              void* d_out, int out_size, void* d_ws, size_t ws_size,
                              hipStream_t stream) {
    const float* x  = (const float*)d_in[0];   // f32 [N,128]
    const int* edge = (const int*)d_in[1];     // int32 [2,E]
    const float* W1 = (const float*)d_in[2];   // f32 [128,64]
    const float* b1 = (const float*)d_in[3];   // f32 [64]
    const float* W2 = (const float*)d_in[4];   // f32 [64,40]
    const float* b2 = (const float*)d_in[5];   // f32 [40]
    float* out      = (float*)d_out;           // f32 [N,40]

    const int n = in_sizes[0] / IN_CH;   // 100000
    const int e = in_sizes[1] / 2;       // 1600000
    const int* srcs = edge;
    const int* dsts = edge + e;

    // workspace layout: ~62 MB total
    int*      counts    = (int*)d_ws;                       // NPAD
    int*      row_start = counts + NPAD;                    // NPAD (needs n+1)
    int*      cursor    = row_start + NPAD;                 // NPAD
    int*      partials  = cursor + NPAD;                    // 512
    float*    dinv      = (float*)(partials + 512);         // NPAD
    int2*     ew        = (int2*)(dinv + NPAD);             // NEDGES (src, w) 8B
    ushort_t* Wp        = (ushort_t*)(ew + NEDGES);         // 8192 bf16
    ushort_t* hw1       = Wp + 8192;                        // N*64 bf16
    float*    h         = (float*)(hw1 + (size_t)NNODES * HID); // N*64 f32
    ushort_t* hw2       = (ushort_t*)(h + (size_t)NNODES * HID); // N*40 bf16

    const int nb = (n + 255) / 256;  // 391

    hipMemsetAsync(counts, 0, (size_t)NPAD * sizeof(int), stream);
    k_hist<<<(e + 255) / 256, 256, 0, stream>>>(dsts, counts, e);
    k_scan1<<<nb, 256, 0, stream>>>(counts, row_start, partials, n);
    k_scan2<<<1, 512, 0, stream>>>(partials, nb);
    k_scan3<<<nb, 256, 0, stream>>>(counts, partials, row_start, cursor, dinv, n, e);
    k_scatter<<<NCHUNK * NRANGE, 256, 0, stream>>>(srcs, dsts, dinv, cursor, ew, e);

    k_prepw<<<32, 256, 0, stream>>>(W1, Wp);
    k_gemm1<<<(n + 63) / 64, 256, 0, stream>>>(x, Wp, hw1, n);
    k_agg1<<<(n + 3) / 4, 256, 0, stream>>>(row_start, ew, dinv, (const uint_t*)hw1, b1, h, n);
    k_gemm2<<<nb, 256, 0, stream>>>(h, W2, hw2, n);
    k_agg2<<<(n + 3) / 4, 256, 0, stream>>>(row_start, ew, dinv, (const uint_t*)hw2, b2, out, n);
}

// Round 7
// 357.839 us; speedup vs baseline: 1.2069x; 1.2069x over previous
//
#include <hip/hip_runtime.h>
#include <hip/hip_bf16.h>

#define NNODES 100000
#define NEDGES 1600000
#define IN_CH 128
#define HID 64
#define NC 40
#define NPAD 100352   // NNODES padded to multiple of 256
#define NBUK 196      // ceil(100000 / 512) dst-buckets of 512 nodes
#define BCHUNK 4096
#define NBIN 391      // ceil(NEDGES / BCHUNK)

typedef unsigned short ushort_t;
typedef unsigned int uint_t;
typedef __attribute__((ext_vector_type(8))) short short8;
typedef __attribute__((ext_vector_type(4))) float floatx4;

__device__ __forceinline__ float bf2f(ushort_t u) {
    union { unsigned int i; float f; } t;
    t.i = ((unsigned int)u) << 16;
    return t.f;
}
__device__ __forceinline__ ushort_t f2bf(float f) {
    union { float ff; unsigned int i; } t;
    t.ff = f;
    unsigned int r = t.i + 0x7fff + ((t.i >> 16) & 1);  // RNE
    return (ushort_t)(r >> 16);
}
// unpack packed bf16x2 (low = even feature, high = odd feature)
__device__ __forceinline__ float2 unpk(uint_t p) {
    union { unsigned int i; float f; } a, b;
    a.i = p << 16;
    b.i = p & 0xffff0000u;
    return make_float2(a.f, b.f);
}

// ---- CSR build: histogram of dst ----
__global__ void k_hist(const int* __restrict__ dsts, int* __restrict__ counts, int e) {
    int i = blockIdx.x * blockDim.x + threadIdx.x;
    if (i < e) atomicAdd(&counts[dsts[i]], 1);
}

// block-local exclusive scan (256 wide), block totals to partials
__global__ __launch_bounds__(256) void k_scan1(const int* __restrict__ counts,
                                               int* __restrict__ excl, int* __restrict__ partials, int n) {
    __shared__ int s[256];
    int t = threadIdx.x;
    int i = blockIdx.x * 256 + t;
    int c = (i < n) ? counts[i] : 0;
    s[t] = c;
    __syncthreads();
    for (int off = 1; off < 256; off <<= 1) {
        int v = (t >= off) ? s[t - off] : 0;
        __syncthreads();
        s[t] += v;
        __syncthreads();
    }
    if (i < n) excl[i] = s[t] - c;
    if (t == 255) partials[blockIdx.x] = s[t];
}

// scan the 391 block totals (single block)
__global__ __launch_bounds__(512) void k_scan2(int* __restrict__ partials, int nb) {
    __shared__ int s[512];
    int t = threadIdx.x;
    int c = (t < nb) ? partials[t] : 0;
    s[t] = c;
    __syncthreads();
    for (int off = 1; off < 512; off <<= 1) {
        int v = (t >= off) ? s[t - off] : 0;
        __syncthreads();
        s[t] += v;
        __syncthreads();
    }
    if (t < nb) partials[t] = s[t] - c;  // exclusive
}

// fixup: final row_start, dinv, per-bucket global cursors
__global__ void k_scan3(const int* __restrict__ counts, const int* __restrict__ partials,
                        int* __restrict__ row_start, float* __restrict__ dinv,
                        int* __restrict__ gcur, int n, int e) {
    int i = blockIdx.x * blockDim.x + threadIdx.x;
    if (i < n) {
        int rs = row_start[i] + partials[i >> 8];
        row_start[i] = rs;
        dinv[i] = rsqrtf((float)counts[i] + 1.0f);
        if (i == 0) row_start[n] = e;
    }
}
// bucket cursor init (after row_start finalized): gcur[b] = row_start[b*512]
__global__ void k_binit(const int* __restrict__ row_start, int* __restrict__ gcur) {
    int b = threadIdx.x + blockIdx.x * 256;
    if (b < NBUK) gcur[b] = row_start[b << 9];
}

// ---- phase 1: bin edges into 196 dst-buckets, LDS-packed burst writes ----
// tmp entry: src (17b) | local_d (9b) << 17  -> 4 B
__global__ __launch_bounds__(256) void k_bin(
    const int* __restrict__ srcs, const int* __restrict__ dsts,
    int* __restrict__ gcur, uint_t* __restrict__ tmp, int e)
{
    __shared__ uint_t pk[BCHUNK];    // 16 KB
    __shared__ ushort_t bk[BCHUNK];  // 8 KB
    __shared__ int hist[NBUK];
    __shared__ int base[NBUK];
    int t = threadIdx.x;
    int begin = blockIdx.x * BCHUNK;
    int cnt = e - begin; if (cnt > BCHUNK) cnt = BCHUNK;

    for (int i = t; i < NBUK; i += 256) hist[i] = 0;
    __syncthreads();
    for (int j = t; j < cnt; j += 256) {
        int d = dsts[begin + j];
        int s = srcs[begin + j];
        int b = d >> 9;
        pk[j] = (uint_t)s | ((uint_t)(d & 511) << 17);
        bk[j] = (ushort_t)b;
        atomicAdd(&hist[b], 1);
    }
    __syncthreads();
    for (int i = t; i < NBUK; i += 256) {
        base[i] = atomicAdd(&gcur[i], hist[i]);  // reserve bucket segment
        hist[i] = 0;                             // reuse as local rank cursor
    }
    __syncthreads();
    for (int j = t; j < cnt; j += 256) {
        int b = bk[j];
        int r = atomicAdd(&hist[b], 1);
        tmp[base[b] + r] = pk[j];  // ~21-edge bursts per (block,bucket)
    }
}

// ---- phase 2: per-bucket counting sort into exact CSR order; emit (src, w) ----
__global__ __launch_bounds__(256) void k_sort(
    const uint_t* __restrict__ tmp, const int* __restrict__ row_start,
    const float* __restrict__ dinv, int2* __restrict__ ew, int n)
{
    __shared__ int cur[512];
    int t = threadIdx.x;
    int d0 = blockIdx.x << 9;
    int nn = n - d0; if (nn > 512) nn = 512;
    for (int i = t; i < nn; i += 256) cur[i] = row_start[d0 + i];
    __syncthreads();
    int rs = row_start[d0];
    int hi = d0 + 512; if (hi > n) hi = n;
    int re = row_start[hi];
    for (int j = rs + t; j < re; j += 256) {
        uint_t p = tmp[j];                 // coalesced
        int s = (int)(p & 0x1FFFFu);
        int ld = (int)(p >> 17);
        int pos = atomicAdd(&cur[ld], 1);
        float w = dinv[s] * dinv[d0 + ld];
        ew[pos] = make_int2(s, __float_as_int(w));  // confined to this block's 64 KB window
    }
}

// ---- pre-swizzle W1 (f32) into bf16 B-fragment order ----
__global__ void k_prepw(const float* __restrict__ W1, ushort_t* __restrict__ Wp) {
    int i = blockIdx.x * 256 + threadIdx.x;
    if (i >= IN_CH * HID) return;
    int j = i & 7;
    int m = (i >> 3) & 15;
    int ct = (i >> 7) & 3;
    int quad = (i >> 9) & 3;
    int kc = i >> 11;
    int k = kc * 32 + quad * 8 + j;
    int c = ct * 16 + m;
    Wp[i] = f2bf(W1[k * HID + c]);
}

// ---- GEMM1: hw1 = bf16(x @ W1) via MFMA ----
__global__ __launch_bounds__(256) void k_gemm1(
    const float* __restrict__ x, const ushort_t* __restrict__ Wp,
    ushort_t* __restrict__ hw1, int n)
{
    int wave = threadIdx.x >> 6;
    int lane = threadIdx.x & 63;
    int m = lane & 15;
    int quad = lane >> 4;
    int row = blockIdx.x * 64 + wave * 16 + m;
    int rowc = row < n ? row : (n - 1);
    const float* xr = x + (size_t)rowc * IN_CH + quad * 8;

    floatx4 acc[4];
#pragma unroll
    for (int ct = 0; ct < 4; ++ct) acc[ct] = (floatx4){0.f, 0.f, 0.f, 0.f};

#pragma unroll
    for (int kc = 0; kc < 4; ++kc) {
        float4 xa = *(const float4*)(xr + kc * 32);
        float4 xb = *(const float4*)(xr + kc * 32 + 4);
        short8 a;
        a[0] = (short)f2bf(xa.x); a[1] = (short)f2bf(xa.y);
        a[2] = (short)f2bf(xa.z); a[3] = (short)f2bf(xa.w);
        a[4] = (short)f2bf(xb.x); a[5] = (short)f2bf(xb.y);
        a[6] = (short)f2bf(xb.z); a[7] = (short)f2bf(xb.w);
#pragma unroll
        for (int ct = 0; ct < 4; ++ct) {
            short8 b = *(const short8*)(Wp + ((((kc * 4 + quad) * 4 + ct) * 16 + m) << 3));
            acc[ct] = __builtin_amdgcn_mfma_f32_16x16x32_bf16(a, b, acc[ct], 0, 0, 0);
        }
    }
    int r0 = blockIdx.x * 64 + wave * 16 + quad * 4;
#pragma unroll
    for (int r = 0; r < 4; ++r) {
        int rr = r0 + r;
        if (rr < n) {
            ushort_t* o = hw1 + (size_t)rr * HID + m;
#pragma unroll
            for (int ct = 0; ct < 4; ++ct) o[ct * 16] = f2bf(acc[ct][r]);
        }
    }
}

// ---- agg1: one wave per node, half-wave = edge, lane = feature pair ----
__global__ __launch_bounds__(256) void k_agg1(
    const int* __restrict__ row_start, const int2* __restrict__ ew,
    const float* __restrict__ dinv, const uint_t* __restrict__ hw1u,
    const float* __restrict__ b1, float* __restrict__ h, int n)
{
    int node = blockIdx.x * 4 + (threadIdx.x >> 6);
    if (node >= n) return;
    int lane = threadIdx.x & 63;
    int half = lane >> 5;
    int l = lane & 31;
    int rs = row_start[node];
    int re = row_start[node + 1];
    float di = dinv[node];

    float2 acc0 = make_float2(0.f, 0.f), acc1 = make_float2(0.f, 0.f);
    if (half == 0) {
        float2 v = unpk(hw1u[node * 32 + l]);
        float sl = di * di;
        acc0.x = v.x * sl; acc0.y = v.y * sl;
    }
    int kb = rs;
    for (; kb + 7 < re; kb += 8) {
        int base = kb + half * 4;
        int2 e0 = ew[base], e1 = ew[base + 1], e2 = ew[base + 2], e3 = ew[base + 3];
        uint_t p0 = hw1u[e0.x * 32 + l];
        uint_t p1 = hw1u[e1.x * 32 + l];
        uint_t p2 = hw1u[e2.x * 32 + l];
        uint_t p3 = hw1u[e3.x * 32 + l];
        float w0 = __int_as_float(e0.y), w1 = __int_as_float(e1.y);
        float w2 = __int_as_float(e2.y), w3 = __int_as_float(e3.y);
        float2 v0 = unpk(p0), v1 = unpk(p1), v2 = unpk(p2), v3 = unpk(p3);
        acc0.x += v0.x * w0; acc0.y += v0.y * w0;
        acc1.x += v1.x * w1; acc1.y += v1.y * w1;
        acc0.x += v2.x * w2; acc0.y += v2.y * w2;
        acc1.x += v3.x * w3; acc1.y += v3.y * w3;
    }
    for (int k = kb + half; k < re; k += 2) {
        int2 e0 = ew[k];
        float2 v = unpk(hw1u[e0.x * 32 + l]);
        float w = __int_as_float(e0.y);
        acc1.x += v.x * w; acc1.y += v.y * w;
    }
    float ax = (acc0.x + acc1.x), ay = (acc0.y + acc1.y);
    ax += __shfl_xor(ax, 32);
    ay += __shfl_xor(ay, 32);
    if (half == 0) {
        float2 b = ((const float2*)b1)[l];
        float vx = ax + b.x, vy = ay + b.y;
        vx = vx > 0.f ? vx : 0.f;
        vy = vy > 0.f ? vy : 0.f;
        ((float2*)h)[node * 32 + l] = make_float2(vx, vy);
    }
}

// ---- GEMM2: hw2 = bf16(h @ W2) (f32 vector ALU, W2 in LDS) ----
__global__ __launch_bounds__(256) void k_gemm2(
    const float* __restrict__ h, const float* __restrict__ W2,
    ushort_t* __restrict__ hw2, int n)
{
    __shared__ float wsm[HID * NC];  // 10 KB
    for (int i = threadIdx.x; i < HID * NC; i += 256) wsm[i] = W2[i];
    __syncthreads();
    int row = blockIdx.x * 256 + threadIdx.x;
    if (row >= n) return;
    const float4* hr = (const float4*)(h + (size_t)row * HID);
    float acc[NC];
#pragma unroll
    for (int c = 0; c < NC; ++c) acc[c] = 0.f;
#pragma unroll 4
    for (int k4 = 0; k4 < HID / 4; ++k4) {
        float4 hv = hr[k4];
        const float* w0 = wsm + (k4 * 4) * NC;
#pragma unroll
        for (int c = 0; c < NC; ++c)
            acc[c] += hv.x * w0[c] + hv.y * w0[c + NC] + hv.z * w0[c + 2 * NC] + hv.w * w0[c + 3 * NC];
    }
    unsigned int* o = (unsigned int*)(hw2 + (size_t)row * NC);
#pragma unroll
    for (int c2 = 0; c2 < NC / 2; ++c2)
        o[c2] = (unsigned int)f2bf(acc[2 * c2]) | ((unsigned int)f2bf(acc[2 * c2 + 1]) << 16);
}

// ---- agg2: one wave per node, half-wave = edge, lanes 0..19 per half = class pairs ----
__global__ __launch_bounds__(256) void k_agg2(
    const int* __restrict__ row_start, const int2* __restrict__ ew,
    const float* __restrict__ dinv, const uint_t* __restrict__ hw2u,
    const float* __restrict__ b2, float* __restrict__ out, int n)
{
    int node = blockIdx.x * 4 + (threadIdx.x >> 6);
    if (node >= n) return;
    int lane = threadIdx.x & 63;
    int half = lane >> 5;
    int l = lane & 31;
    int li = l < 20 ? l : 0;
    int rs = row_start[node];
    int re = row_start[node + 1];
    float di = dinv[node];

    float2 acc0 = make_float2(0.f, 0.f), acc1 = make_float2(0.f, 0.f);
    if (half == 0) {
        float2 v = unpk(hw2u[node * 20 + li]);
        float sl = di * di;
        acc0.x = v.x * sl; acc0.y = v.y * sl;
    }
    int kb = rs;
    for (; kb + 7 < re; kb += 8) {
        int base = kb + half * 4;
        int2 e0 = ew[base], e1 = ew[base + 1], e2 = ew[base + 2], e3 = ew[base + 3];
        uint_t p0 = hw2u[e0.x * 20 + li];
        uint_t p1 = hw2u[e1.x * 20 + li];
        uint_t p2 = hw2u[e2.x * 20 + li];
        uint_t p3 = hw2u[e3.x * 20 + li];
        float w0 = __int_as_float(e0.y), w1 = __int_as_float(e1.y);
        float w2 = __int_as_float(e2.y), w3 = __int_as_float(e3.y);
        float2 v0 = unpk(p0), v1 = unpk(p1), v2 = unpk(p2), v3 = unpk(p3);
        acc0.x += v0.x * w0; acc0.y += v0.y * w0;
        acc1.x += v1.x * w1; acc1.y += v1.y * w1;
        acc0.x += v2.x * w2; acc0.y += v2.y * w2;
        acc1.x += v3.x * w3; acc1.y += v3.y * w3;
    }
    for (int k = kb + half; k < re; k += 2) {
        int2 e0 = ew[k];
        float2 v = unpk(hw2u[e0.x * 20 + li]);
        float w = __int_as_float(e0.y);
        acc1.x += v.x * w; acc1.y += v.y * w;
    }
    float ax = (acc0.x + acc1.x), ay = (acc0.y + acc1.y);
    ax += __shfl_xor(ax, 32);
    ay += __shfl_xor(ay, 32);
    if (half == 0 && l < 20) {
        float2 b = ((const float2*)b2)[l];
        ((float2*)out)[node * 20 + l] = make_float2(ax + b.x, ay + b.y);
    }
}

extern "C" void kernel_launch(void* const* d_in, const int* in_sizes, int n_in,
                              void* d_out, int out_size, void* d_ws, size_t ws_size,
                              hipStream_t stream) {
    const float* x  = (const float*)d_in[0];   // f32 [N,128]
    const int* edge = (const int*)d_in[1];     // int32 [2,E]
    const float* W1 = (const float*)d_in[2];   // f32 [128,64]
    const float* b1 = (const float*)d_in[3];   // f32 [64]
    const float* W2 = (const float*)d_in[4];   // f32 [64,40]
    const float* b2 = (const float*)d_in[5];   // f32 [40]
    float* out      = (float*)d_out;           // f32 [N,40]

    const int n = in_sizes[0] / IN_CH;   // 100000
    const int e = in_sizes[1] / 2;       // 1600000
    const int* srcs = edge;
    const int* dsts = edge + e;

    // workspace layout: ~62 MB total
    int*      counts    = (int*)d_ws;                       // NPAD
    int*      row_start = counts + NPAD;                    // NPAD (needs n+1)
    int*      gcur      = row_start + NPAD;                 // 256
    int*      partials  = gcur + 256;                       // 512
    float*    dinv      = (float*)(partials + 512);         // NPAD
    uint_t*   tmp       = (uint_t*)(dinv + NPAD);           // NEDGES packed 4B
    int2*     ew        = (int2*)(tmp + NEDGES);            // NEDGES (src, w) 8B
    ushort_t* Wp        = (ushort_t*)(ew + NEDGES);         // 8192 bf16
    ushort_t* hw1       = Wp + 8192;                        // N*64 bf16
    float*    h         = (float*)(hw1 + (size_t)NNODES * HID); // N*64 f32
    ushort_t* hw2       = (ushort_t*)(h + (size_t)NNODES * HID); // N*40 bf16

    const int nb = (n + 255) / 256;  // 391

    hipMemsetAsync(counts, 0, (size_t)NPAD * sizeof(int), stream);
    k_hist<<<(e + 255) / 256, 256, 0, stream>>>(dsts, counts, e);
    k_scan1<<<nb, 256, 0, stream>>>(counts, row_start, partials, n);
    k_scan2<<<1, 512, 0, stream>>>(partials, nb);
    k_scan3<<<nb, 256, 0, stream>>>(counts, partials, row_start, dinv, gcur, n, e);
    k_binit<<<1, 256, 0, stream>>>(row_start, gcur);
    k_bin<<<NBIN, 256, 0, stream>>>(srcs, dsts, gcur, tmp, e);
    k_sort<<<NBUK, 256, 0, stream>>>(tmp, row_start, dinv, ew, n);

    k_prepw<<<32, 256, 0, stream>>>(W1, Wp);
    k_gemm1<<<(n + 63) / 64, 256, 0, stream>>>(x, Wp, hw1, n);
    k_agg1<<<(n + 3) / 4, 256, 0, stream>>>(row_start, ew, dinv, (const uint_t*)hw1, b1, h, n);
    k_gemm2<<<nb, 256, 0, stream>>>(h, W2, hw2, n);
    k_agg2<<<(n + 3) / 4, 256, 0, stream>>>(row_start, ew, dinv, (const uint_t*)hw2, b2, out, n);
}

// Round 8
// 296.375 us; speedup vs baseline: 1.4572x; 1.2074x over previous
//
#include <hip/hip_runtime.h>
#include <hip/hip_bf16.h>

#define NNODES 100000
#define NEDGES 1600000
#define IN_CH 128
#define HID 64
#define NC 40
#define NPAD 100352   // NNODES padded to multiple of 256
#define NBUK 196      // ceil(100000 / 512) dst-buckets of 512 nodes
#define CAP 9216      // per-bucket tmp capacity (mean 8192, sigma ~90 -> 11 sigma)
#define BCHUNK 4096
#define NBIN 391      // ceil(NEDGES / BCHUNK)

typedef unsigned short ushort_t;
typedef unsigned int uint_t;
typedef __attribute__((ext_vector_type(8))) short short8;
typedef __attribute__((ext_vector_type(4))) float floatx4;

__device__ __forceinline__ float bf2f(ushort_t u) {
    union { unsigned int i; float f; } t;
    t.i = ((unsigned int)u) << 16;
    return t.f;
}
__device__ __forceinline__ ushort_t f2bf(float f) {
    union { float ff; unsigned int i; } t;
    t.ff = f;
    unsigned int r = t.i + 0x7fff + ((t.i >> 16) & 1);  // RNE
    return (ushort_t)(r >> 16);
}
// unpack packed bf16x2
__device__ __forceinline__ float2 unpk(uint_t p) {
    union { unsigned int i; float f; } a, b;
    a.i = p << 16;
    b.i = p & 0xffff0000u;
    return make_float2(a.f, b.f);
}

// ---- gcur[b] = b*CAP ----
__global__ void k_ginit(int* __restrict__ gcur) {
    int b = threadIdx.x;
    if (b < NBUK) gcur[b] = b * CAP;
}

// ---- bin edges into bucket-major tmp; entry: src(17b) | local_d(9b)<<17 ----
__global__ __launch_bounds__(256) void k_bin0(
    const int* __restrict__ srcs, const int* __restrict__ dsts,
    int* __restrict__ gcur, uint_t* __restrict__ tmp, int e)
{
    __shared__ uint_t pk[BCHUNK];    // 16 KB
    __shared__ ushort_t bk[BCHUNK];  // 8 KB
    __shared__ int hist[NBUK];
    __shared__ int base[NBUK];
    int t = threadIdx.x;
    int begin = blockIdx.x * BCHUNK;
    int cnt = e - begin; if (cnt > BCHUNK) cnt = BCHUNK;

    for (int i = t; i < NBUK; i += 256) hist[i] = 0;
    __syncthreads();
    for (int j = t; j < cnt; j += 256) {
        int d = dsts[begin + j];
        int s = srcs[begin + j];
        int b = d >> 9;
        pk[j] = (uint_t)s | ((uint_t)(d & 511) << 17);
        bk[j] = (ushort_t)b;
        atomicAdd(&hist[b], 1);
    }
    __syncthreads();
    for (int i = t; i < NBUK; i += 256) {
        base[i] = atomicAdd(&gcur[i], hist[i]);  // reserve segment in bucket i
        hist[i] = 0;                             // reuse as local rank cursor
    }
    __syncthreads();
    for (int j = t; j < cnt; j += 256) {
        int b = bk[j];
        int r = atomicAdd(&hist[b], 1);
        int pos = base[b] + r;
        if (pos < (b + 1) * CAP) tmp[pos] = pk[j];  // burst writes; guard vs overflow
    }
}

// ---- exclusive scan of bucket totals -> bbase[0..NBUK], single block ----
__global__ __launch_bounds__(256) void k_bbase(const int* __restrict__ gcur,
                                               int* __restrict__ bbase, int e) {
    __shared__ int s[256];
    int t = threadIdx.x;
    int c = (t < NBUK) ? (gcur[t] - t * CAP) : 0;
    s[t] = c;
    __syncthreads();
    for (int off = 1; off < 256; off <<= 1) {
        int v = (t >= off) ? s[t - off] : 0;
        __syncthreads();
        s[t] += v;
        __syncthreads();
    }
    if (t < NBUK) bbase[t] = s[t] - c;
    if (t == 0) bbase[NBUK] = e;
}

// ---- per-bucket: count per node (LDS), scan 512, write row_start + dinv ----
__global__ __launch_bounds__(256) void k_sort_a(
    const uint_t* __restrict__ tmp, const int* __restrict__ gcur,
    const int* __restrict__ bbase, int* __restrict__ row_start,
    float* __restrict__ dinv, int n, int e)
{
    __shared__ int cnt[512];
    __shared__ int sc[512];
    int t = threadIdx.x;
    int b = blockIdx.x;
    int d0 = b << 9;
    int total = gcur[b] - b * CAP;
    cnt[t] = 0; cnt[t + 256] = 0;
    __syncthreads();
    const uint_t* seg = tmp + b * CAP;
    for (int j = t; j < total; j += 256)
        atomicAdd(&cnt[seg[j] >> 17], 1);
    __syncthreads();
    sc[t] = cnt[t]; sc[t + 256] = cnt[t + 256];
    __syncthreads();
    for (int off = 1; off < 512; off <<= 1) {
        int v0 = (t >= off) ? sc[t - off] : 0;
        int i1 = t + 256;
        int v1 = (i1 >= off) ? sc[i1 - off] : 0;
        __syncthreads();
        sc[t] += v0; sc[i1] += v1;
        __syncthreads();
    }
    int gb = bbase[b];
#pragma unroll
    for (int q = 0; q < 2; ++q) {
        int i = t + q * 256;
        int node = d0 + i;
        if (node < n) {
            row_start[node] = gb + sc[i] - cnt[i];
            dinv[node] = rsqrtf((float)cnt[i] + 1.0f);
        }
    }
    if (b == NBUK - 1 && t == 0) row_start[n] = e;
}

// ---- per-bucket: scatter to final CSR order; emit (src, w) in 64 KB window ----
__global__ __launch_bounds__(256) void k_sort_b(
    const uint_t* __restrict__ tmp, const int* __restrict__ gcur,
    const int* __restrict__ row_start, const float* __restrict__ dinv,
    int2* __restrict__ ew, int n)
{
    __shared__ int cur[512];
    int t = threadIdx.x;
    int b = blockIdx.x;
    int d0 = b << 9;
    int total = gcur[b] - b * CAP;
#pragma unroll
    for (int q = 0; q < 2; ++q) {
        int i = t + q * 256;
        int node = d0 + i;
        cur[i] = (node < n) ? row_start[node] : 0;
    }
    __syncthreads();
    const uint_t* seg = tmp + b * CAP;
    for (int j = t; j < total; j += 256) {
        uint_t p = seg[j];                 // coalesced
        int s = (int)(p & 0x1FFFFu);
        int ld = (int)(p >> 17);
        int pos = atomicAdd(&cur[ld], 1);
        float w = dinv[s] * dinv[d0 + ld];
        ew[pos] = make_int2(s, __float_as_int(w));
    }
}

// ---- pre-swizzle W1 (f32) into bf16 B-fragment order ----
__global__ void k_prepw(const float* __restrict__ W1, ushort_t* __restrict__ Wp) {
    int i = blockIdx.x * 256 + threadIdx.x;
    if (i >= IN_CH * HID) return;
    int j = i & 7;
    int m = (i >> 3) & 15;
    int ct = (i >> 7) & 3;
    int quad = (i >> 9) & 3;
    int kc = i >> 11;
    int k = kc * 32 + quad * 8 + j;
    int c = ct * 16 + m;
    Wp[i] = f2bf(W1[k * HID + c]);
}

// ---- GEMM1: hw1 = bf16(x @ W1) via MFMA ----
__global__ __launch_bounds__(256) void k_gemm1(
    const float* __restrict__ x, const ushort_t* __restrict__ Wp,
    ushort_t* __restrict__ hw1, int n)
{
    int wave = threadIdx.x >> 6;
    int lane = threadIdx.x & 63;
    int m = lane & 15;
    int quad = lane >> 4;
    int row = blockIdx.x * 64 + wave * 16 + m;
    int rowc = row < n ? row : (n - 1);
    const float* xr = x + (size_t)rowc * IN_CH + quad * 8;

    floatx4 acc[4];
#pragma unroll
    for (int ct = 0; ct < 4; ++ct) acc[ct] = (floatx4){0.f, 0.f, 0.f, 0.f};

#pragma unroll
    for (int kc = 0; kc < 4; ++kc) {
        float4 xa = *(const float4*)(xr + kc * 32);
        float4 xb = *(const float4*)(xr + kc * 32 + 4);
        short8 a;
        a[0] = (short)f2bf(xa.x); a[1] = (short)f2bf(xa.y);
        a[2] = (short)f2bf(xa.z); a[3] = (short)f2bf(xa.w);
        a[4] = (short)f2bf(xb.x); a[5] = (short)f2bf(xb.y);
        a[6] = (short)f2bf(xb.z); a[7] = (short)f2bf(xb.w);
#pragma unroll
        for (int ct = 0; ct < 4; ++ct) {
            short8 b = *(const short8*)(Wp + ((((kc * 4 + quad) * 4 + ct) * 16 + m) << 3));
            acc[ct] = __builtin_amdgcn_mfma_f32_16x16x32_bf16(a, b, acc[ct], 0, 0, 0);
        }
    }
    int r0 = blockIdx.x * 64 + wave * 16 + quad * 4;
#pragma unroll
    for (int r = 0; r < 4; ++r) {
        int rr = r0 + r;
        if (rr < n) {
            ushort_t* o = hw1 + (size_t)rr * HID + m;
#pragma unroll
            for (int ct = 0; ct < 4; ++ct) o[ct * 16] = f2bf(acc[ct][r]);
        }
    }
}

// ---- agg1: one wave per node, half-wave = edge, lane = feature pair ----
__global__ __launch_bounds__(256) void k_agg1(
    const int* __restrict__ row_start, const int2* __restrict__ ew,
    const float* __restrict__ dinv, const uint_t* __restrict__ hw1u,
    const float* __restrict__ b1, float* __restrict__ h, int n)
{
    int node = blockIdx.x * 4 + (threadIdx.x >> 6);
    if (node >= n) return;
    int lane = threadIdx.x & 63;
    int half = lane >> 5;
    int l = lane & 31;
    int rs = row_start[node];
    int re = row_start[node + 1];
    float di = dinv[node];

    float2 acc0 = make_float2(0.f, 0.f), acc1 = make_float2(0.f, 0.f);
    if (half == 0) {
        float2 v = unpk(hw1u[node * 32 + l]);
        float sl = di * di;
        acc0.x = v.x * sl; acc0.y = v.y * sl;
    }
    int kb = rs;
    for (; kb + 7 < re; kb += 8) {
        int base = kb + half * 4;
        int2 e0 = ew[base], e1 = ew[base + 1], e2 = ew[base + 2], e3 = ew[base + 3];
        uint_t p0 = hw1u[e0.x * 32 + l];
        uint_t p1 = hw1u[e1.x * 32 + l];
        uint_t p2 = hw1u[e2.x * 32 + l];
        uint_t p3 = hw1u[e3.x * 32 + l];
        float w0 = __int_as_float(e0.y), w1 = __int_as_float(e1.y);
        float w2 = __int_as_float(e2.y), w3 = __int_as_float(e3.y);
        float2 v0 = unpk(p0), v1 = unpk(p1), v2 = unpk(p2), v3 = unpk(p3);
        acc0.x += v0.x * w0; acc0.y += v0.y * w0;
        acc1.x += v1.x * w1; acc1.y += v1.y * w1;
        acc0.x += v2.x * w2; acc0.y += v2.y * w2;
        acc1.x += v3.x * w3; acc1.y += v3.y * w3;
    }
    for (int k = kb + half; k < re; k += 2) {
        int2 e0 = ew[k];
        float2 v = unpk(hw1u[e0.x * 32 + l]);
        float w = __int_as_float(e0.y);
        acc1.x += v.x * w; acc1.y += v.y * w;
    }
    float ax = (acc0.x + acc1.x), ay = (acc0.y + acc1.y);
    ax += __shfl_xor(ax, 32);
    ay += __shfl_xor(ay, 32);
    if (half == 0) {
        float2 b = ((const float2*)b1)[l];
        float vx = ax + b.x, vy = ay + b.y;
        vx = vx > 0.f ? vx : 0.f;
        vy = vy > 0.f ? vy : 0.f;
        ((float2*)h)[node * 32 + l] = make_float2(vx, vy);
    }
}

// ---- GEMM2: hw2 = bf16(h @ W2) (f32 vector ALU, W2 in LDS) ----
__global__ __launch_bounds__(256) void k_gemm2(
    const float* __restrict__ h, const float* __restrict__ W2,
    ushort_t* __restrict__ hw2, int n)
{
    __shared__ float wsm[HID * NC];  // 10 KB
    for (int i = threadIdx.x; i < HID * NC; i += 256) wsm[i] = W2[i];
    __syncthreads();
    int row = blockIdx.x * 256 + threadIdx.x;
    if (row >= n) return;
    const float4* hr = (const float4*)(h + (size_t)row * HID);
    float acc[NC];
#pragma unroll
    for (int c = 0; c < NC; ++c) acc[c] = 0.f;
#pragma unroll 4
    for (int k4 = 0; k4 < HID / 4; ++k4) {
        float4 hv = hr[k4];
        const float* w0 = wsm + (k4 * 4) * NC;
#pragma unroll
        for (int c = 0; c < NC; ++c)
            acc[c] += hv.x * w0[c] + hv.y * w0[c + NC] + hv.z * w0[c + 2 * NC] + hv.w * w0[c + 3 * NC];
    }
    unsigned int* o = (unsigned int*)(hw2 + (size_t)row * NC);
#pragma unroll
    for (int c2 = 0; c2 < NC / 2; ++c2)
        o[c2] = (unsigned int)f2bf(acc[2 * c2]) | ((unsigned int)f2bf(acc[2 * c2 + 1]) << 16);
}

// ---- agg2: one wave per node, half-wave = edge, lanes 0..19 per half = class pairs ----
__global__ __launch_bounds__(256) void k_agg2(
    const int* __restrict__ row_start, const int2* __restrict__ ew,
    const float* __restrict__ dinv, const uint_t* __restrict__ hw2u,
    const float* __restrict__ b2, float* __restrict__ out, int n)
{
    int node = blockIdx.x * 4 + (threadIdx.x >> 6);
    if (node >= n) return;
    int lane = threadIdx.x & 63;
    int half = lane >> 5;
    int l = lane & 31;
    int li = l < 20 ? l : 0;
    int rs = row_start[node];
    int re = row_start[node + 1];
    float di = dinv[node];

    float2 acc0 = make_float2(0.f, 0.f), acc1 = make_float2(0.f, 0.f);
    if (half == 0) {
        float2 v = unpk(hw2u[node * 20 + li]);
        float sl = di * di;
        acc0.x = v.x * sl; acc0.y = v.y * sl;
    }
    int kb = rs;
    for (; kb + 7 < re; kb += 8) {
        int base = kb + half * 4;
        int2 e0 = ew[base], e1 = ew[base + 1], e2 = ew[base + 2], e3 = ew[base + 3];
        uint_t p0 = hw2u[e0.x * 20 + li];
        uint_t p1 = hw2u[e1.x * 20 + li];
        uint_t p2 = hw2u[e2.x * 20 + li];
        uint_t p3 = hw2u[e3.x * 20 + li];
        float w0 = __int_as_float(e0.y), w1 = __int_as_float(e1.y);
        float w2 = __int_as_float(e2.y), w3 = __int_as_float(e3.y);
        float2 v0 = unpk(p0), v1 = unpk(p1), v2 = unpk(p2), v3 = unpk(p3);
        acc0.x += v0.x * w0; acc0.y += v0.y * w0;
        acc1.x += v1.x * w1; acc1.y += v1.y * w1;
        acc0.x += v2.x * w2; acc0.y += v2.y * w2;
        acc1.x += v3.x * w3; acc1.y += v3.y * w3;
    }
    for (int k = kb + half; k < re; k += 2) {
        int2 e0 = ew[k];
        float2 v = unpk(hw2u[e0.x * 20 + li]);
        float w = __int_as_float(e0.y);
        acc1.x += v.x * w; acc1.y += v.y * w;
    }
    float ax = (acc0.x + acc1.x), ay = (acc0.y + acc1.y);
    ax += __shfl_xor(ax, 32);
    ay += __shfl_xor(ay, 32);
    if (half == 0 && l < 20) {
        float2 b = ((const float2*)b2)[l];
        ((float2*)out)[node * 20 + l] = make_float2(ax + b.x, ay + b.y);
    }
}

extern "C" void kernel_launch(void* const* d_in, const int* in_sizes, int n_in,
                              void* d_out, int out_size, void* d_ws, size_t ws_size,
                              hipStream_t stream) {
    const float* x  = (const float*)d_in[0];   // f32 [N,128]
    const int* edge = (const int*)d_in[1];     // int32 [2,E]
    const float* W1 = (const float*)d_in[2];   // f32 [128,64]
    const float* b1 = (const float*)d_in[3];   // f32 [64]
    const float* W2 = (const float*)d_in[4];   // f32 [64,40]
    const float* b2 = (const float*)d_in[5];   // f32 [40]
    float* out      = (float*)d_out;           // f32 [N,40]

    const int n = in_sizes[0] / IN_CH;   // 100000
    const int e = in_sizes[1] / 2;       // 1600000
    const int* srcs = edge;
    const int* dsts = edge + e;

    // workspace layout: ~67 MB total
    int*      gcur      = (int*)d_ws;                       // 256
    int*      bbase     = gcur + 256;                       // 256
    int*      row_start = bbase + 256;                      // NPAD (needs n+1)
    float*    dinv      = (float*)(row_start + NPAD);       // NPAD
    uint_t*   tmp       = (uint_t*)(dinv + NPAD);           // NBUK*CAP packed 4B
    int2*     ew        = (int2*)(tmp + (size_t)NBUK * CAP);// NEDGES (src, w) 8B
    ushort_t* Wp        = (ushort_t*)(ew + NEDGES);         // 8192 bf16
    ushort_t* hw1       = Wp + 8192;                        // N*64 bf16
    float*    h         = (float*)(hw1 + (size_t)NNODES * HID); // N*64 f32
    ushort_t* hw2       = (ushort_t*)(h + (size_t)NNODES * HID); // N*40 bf16

    k_ginit<<<1, 256, 0, stream>>>(gcur);
    k_bin0<<<NBIN, 256, 0, stream>>>(srcs, dsts, gcur, tmp, e);
    k_bbase<<<1, 256, 0, stream>>>(gcur, bbase, e);
    k_sort_a<<<NBUK, 256, 0, stream>>>(tmp, gcur, bbase, row_start, dinv, n, e);
    k_sort_b<<<NBUK, 256, 0, stream>>>(tmp, gcur, row_start, dinv, ew, n);

    k_prepw<<<32, 256, 0, stream>>>(W1, Wp);
    k_gemm1<<<(n + 63) / 64, 256, 0, stream>>>(x, Wp, hw1, n);
    k_agg1<<<(n + 3) / 4, 256, 0, stream>>>(row_start, ew, dinv, (const uint_t*)hw1, b1, h, n);
    k_gemm2<<<(n + 255) / 256, 256, 0, stream>>>(h, W2, hw2, n);
    k_agg2<<<(n + 3) / 4, 256, 0, stream>>>(row_start, ew, dinv, (const uint_t*)hw2, b2, out, n);
}

// Round 10
// 280.194 us; speedup vs baseline: 1.5413x; 1.0578x over previous
//
#include <hip/hip_runtime.h>
#include <hip/hip_bf16.h>

#define NNODES 100000
#define NEDGES 1600000
#define IN_CH 128
#define HID 64
#define NC 40
#define NPAD 100352   // NNODES padded to multiple of 256
#define NBUK 196      // ceil(100000 / 512) dst-buckets of 512 nodes
#define CAP 9216      // per-bucket tmp capacity (mean 8192, sigma ~90 -> 11 sigma)
#define BCHUNK 4096
#define NBIN 391      // ceil(NEDGES / BCHUNK)

typedef unsigned short ushort_t;
typedef unsigned int uint_t;
typedef __attribute__((ext_vector_type(8))) short short8;
typedef __attribute__((ext_vector_type(4))) float floatx4;

__device__ __forceinline__ float bf2f(ushort_t u) {
    union { unsigned int i; float f; } t;
    t.i = ((unsigned int)u) << 16;
    return t.f;
}
__device__ __forceinline__ ushort_t f2bf(float f) {
    union { float ff; unsigned int i; } t;
    t.ff = f;
    unsigned int r = t.i + 0x7fff + ((t.i >> 16) & 1);  // RNE
    return (ushort_t)(r >> 16);
}
// unpack packed bf16x2
__device__ __forceinline__ float2 unpk(uint_t p) {
    union { unsigned int i; float f; } a, b;
    a.i = p << 16;
    b.i = p & 0xffff0000u;
    return make_float2(a.f, b.f);
}

// ---- gcur[b] = b*CAP ----
__global__ void k_ginit(int* __restrict__ gcur) {
    int b = threadIdx.x;
    if (b < NBUK) gcur[b] = b * CAP;
}

// ---- bin edges into bucket-major tmp; entry: src(17b) | local_d(9b)<<17 ----
__global__ __launch_bounds__(256) void k_bin0(
    const int* __restrict__ srcs, const int* __restrict__ dsts,
    int* __restrict__ gcur, uint_t* __restrict__ tmp, int e)
{
    __shared__ uint_t pk[BCHUNK];    // 16 KB
    __shared__ ushort_t bk[BCHUNK];  // 8 KB
    __shared__ int hist[NBUK];
    __shared__ int base[NBUK];
    int t = threadIdx.x;
    int begin = blockIdx.x * BCHUNK;
    int cnt = e - begin; if (cnt > BCHUNK) cnt = BCHUNK;

    for (int i = t; i < NBUK; i += 256) hist[i] = 0;
    __syncthreads();
    for (int j = t; j < cnt; j += 256) {
        int d = dsts[begin + j];
        int s = srcs[begin + j];
        int b = d >> 9;
        pk[j] = (uint_t)s | ((uint_t)(d & 511) << 17);
        bk[j] = (ushort_t)b;
        atomicAdd(&hist[b], 1);
    }
    __syncthreads();
    for (int i = t; i < NBUK; i += 256) {
        base[i] = atomicAdd(&gcur[i], hist[i]);  // reserve segment in bucket i
        hist[i] = 0;                             // reuse as local rank cursor
    }
    __syncthreads();
    for (int j = t; j < cnt; j += 256) {
        int b = bk[j];
        int r = atomicAdd(&hist[b], 1);
        int pos = base[b] + r;
        if (pos < (b + 1) * CAP) tmp[pos] = pk[j];  // burst writes; guard vs overflow
    }
}

// ---- exclusive scan of bucket totals -> bbase[0..NBUK], single block ----
__global__ __launch_bounds__(256) void k_bbase(const int* __restrict__ gcur,
                                               int* __restrict__ bbase, int e) {
    __shared__ int s[256];
    int t = threadIdx.x;
    int c = (t < NBUK) ? (gcur[t] - t * CAP) : 0;
    s[t] = c;
    __syncthreads();
    for (int off = 1; off < 256; off <<= 1) {
        int v = (t >= off) ? s[t - off] : 0;
        __syncthreads();
        s[t] += v;
        __syncthreads();
    }
    if (t < NBUK) bbase[t] = s[t] - c;
    if (t == 0) bbase[NBUK] = e;
}

// ---- per-bucket: count per node (LDS), scan 512, write row_start + dinv ----
__global__ __launch_bounds__(256) void k_sort_a(
    const uint_t* __restrict__ tmp, const int* __restrict__ gcur,
    const int* __restrict__ bbase, int* __restrict__ row_start,
    float* __restrict__ dinv, int n, int e)
{
    __shared__ int cnt[512];
    __shared__ int sc[512];
    int t = threadIdx.x;
    int b = blockIdx.x;
    int d0 = b << 9;
    int total = gcur[b] - b * CAP;
    cnt[t] = 0; cnt[t + 256] = 0;
    __syncthreads();
    const uint_t* seg = tmp + b * CAP;
    for (int j = t; j < total; j += 256)
        atomicAdd(&cnt[seg[j] >> 17], 1);
    __syncthreads();
    sc[t] = cnt[t]; sc[t + 256] = cnt[t + 256];
    __syncthreads();
    for (int off = 1; off < 512; off <<= 1) {
        int v0 = (t >= off) ? sc[t - off] : 0;
        int i1 = t + 256;
        int v1 = (i1 >= off) ? sc[i1 - off] : 0;
        __syncthreads();
        sc[t] += v0; sc[i1] += v1;
        __syncthreads();
    }
    int gb = bbase[b];
#pragma unroll
    for (int q = 0; q < 2; ++q) {
        int i = t + q * 256;
        int node = d0 + i;
        if (node < n) {
            row_start[node] = gb + sc[i] - cnt[i];
            dinv[node] = rsqrtf((float)cnt[i] + 1.0f);
        }
    }
    if (b == NBUK - 1 && t == 0) row_start[n] = e;
}

// ---- per-bucket: scatter to final CSR order; emit (src, w) in 64 KB window ----
__global__ __launch_bounds__(256) void k_sort_b(
    const uint_t* __restrict__ tmp, const int* __restrict__ gcur,
    const int* __restrict__ row_start, const float* __restrict__ dinv,
    int2* __restrict__ ew, int n)
{
    __shared__ int cur[512];
    int t = threadIdx.x;
    int b = blockIdx.x;
    int d0 = b << 9;
    int total = gcur[b] - b * CAP;
#pragma unroll
    for (int q = 0; q < 2; ++q) {
        int i = t + q * 256;
        int node = d0 + i;
        cur[i] = (node < n) ? row_start[node] : 0;
    }
    __syncthreads();
    const uint_t* seg = tmp + b * CAP;
    for (int j = t; j < total; j += 256) {
        uint_t p = seg[j];                 // coalesced
        int s = (int)(p & 0x1FFFFu);
        int ld = (int)(p >> 17);
        int pos = atomicAdd(&cur[ld], 1);
        float w = dinv[s] * dinv[d0 + ld];
        ew[pos] = make_int2(s, __float_as_int(w));
    }
}

// ---- pre-swizzle W1 (f32) into bf16 B-fragment order ----
__global__ void k_prepw(const float* __restrict__ W1, ushort_t* __restrict__ Wp) {
    int i = blockIdx.x * 256 + threadIdx.x;
    if (i >= IN_CH * HID) return;
    int j = i & 7;
    int m = (i >> 3) & 15;
    int ct = (i >> 7) & 3;
    int quad = (i >> 9) & 3;
    int kc = i >> 11;
    int k = kc * 32 + quad * 8 + j;
    int c = ct * 16 + m;
    Wp[i] = f2bf(W1[k * HID + c]);
}

// ---- GEMM1: hw1 = bf16(x @ W1) via MFMA ----
__global__ __launch_bounds__(256) void k_gemm1(
    const float* __restrict__ x, const ushort_t* __restrict__ Wp,
    ushort_t* __restrict__ hw1, int n)
{
    int wave = threadIdx.x >> 6;
    int lane = threadIdx.x & 63;
    int m = lane & 15;
    int quad = lane >> 4;
    int row = blockIdx.x * 64 + wave * 16 + m;
    int rowc = row < n ? row : (n - 1);
    const float* xr = x + (size_t)rowc * IN_CH + quad * 8;

    floatx4 acc[4];
#pragma unroll
    for (int ct = 0; ct < 4; ++ct) acc[ct] = (floatx4){0.f, 0.f, 0.f, 0.f};

#pragma unroll
    for (int kc = 0; kc < 4; ++kc) {
        float4 xa = *(const float4*)(xr + kc * 32);
        float4 xb = *(const float4*)(xr + kc * 32 + 4);
        short8 a;
        a[0] = (short)f2bf(xa.x); a[1] = (short)f2bf(xa.y);
        a[2] = (short)f2bf(xa.z); a[3] = (short)f2bf(xa.w);
        a[4] = (short)f2bf(xb.x); a[5] = (short)f2bf(xb.y);
        a[6] = (short)f2bf(xb.z); a[7] = (short)f2bf(xb.w);
#pragma unroll
        for (int ct = 0; ct < 4; ++ct) {
            short8 b = *(const short8*)(Wp + ((((kc * 4 + quad) * 4 + ct) * 16 + m) << 3));
            acc[ct] = __builtin_amdgcn_mfma_f32_16x16x32_bf16(a, b, acc[ct], 0, 0, 0);
        }
    }
    int r0 = blockIdx.x * 64 + wave * 16 + quad * 4;
#pragma unroll
    for (int r = 0; r < 4; ++r) {
        int rr = r0 + r;
        if (rr < n) {
            ushort_t* o = hw1 + (size_t)rr * HID + m;
#pragma unroll
            for (int ct = 0; ct < 4; ++ct) o[ct * 16] = f2bf(acc[ct][r]);
        }
    }
}

// ---- agg1: one wave per node; 64-edge register window + shfl broadcast ----
// lane i of the wave holds edge (base+i); halves process even/odd edges.
// All loops are wave-uniform: lanes beyond the window hold (s=0, w=0), so
// shfl always sources ACTIVE lanes (round-9 bug: divergent remainder loop
// shfl'd from exec-masked lanes -> dropped edges).
__global__ __launch_bounds__(256) void k_agg1(
    const int* __restrict__ row_start, const int2* __restrict__ ew,
    const float* __restrict__ dinv, const uint_t* __restrict__ hw1u,
    const float* __restrict__ b1, float* __restrict__ h, int n)
{
    int node = blockIdx.x * 4 + (threadIdx.x >> 6);
    if (node >= n) return;
    int lane = threadIdx.x & 63;
    int half = lane >> 5;
    int l = lane & 31;
    int rs = row_start[node];
    int re = row_start[node + 1];
    float di = dinv[node];

    float2 acc0 = make_float2(0.f, 0.f), acc1 = make_float2(0.f, 0.f);
    if (half == 0) {
        float2 v = unpk(hw1u[node * 32 + l]);
        float sl = di * di;
        acc0.x = v.x * sl; acc0.y = v.y * sl;
    }
    for (int base = rs; base < re; base += 64) {
        int nw = re - base; if (nw > 64) nw = 64;
        int idx = base + lane;
        int2 el = (idx < re) ? ew[idx] : make_int2(0, 0);  // pad: s=0, w=0
        int j = 0;
        for (; j + 8 <= nw; j += 8) {   // uniform trip count
            int k0 = j + half;  // this half: k0, k0+2, k0+4, k0+6
            int s0 = __shfl(el.x, k0);     float w0 = __int_as_float(__shfl(el.y, k0));
            int s1 = __shfl(el.x, k0 + 2); float w1 = __int_as_float(__shfl(el.y, k0 + 2));
            int s2 = __shfl(el.x, k0 + 4); float w2 = __int_as_float(__shfl(el.y, k0 + 4));
            int s3 = __shfl(el.x, k0 + 6); float w3 = __int_as_float(__shfl(el.y, k0 + 6));
            uint_t p0 = hw1u[s0 * 32 + l];
            uint_t p1 = hw1u[s1 * 32 + l];
            uint_t p2 = hw1u[s2 * 32 + l];
            uint_t p3 = hw1u[s3 * 32 + l];
            float2 v0 = unpk(p0), v1 = unpk(p1), v2 = unpk(p2), v3 = unpk(p3);
            acc0.x += v0.x * w0; acc0.y += v0.y * w0;
            acc1.x += v1.x * w1; acc1.y += v1.y * w1;
            acc0.x += v2.x * w2; acc0.y += v2.y * w2;
            acc1.x += v3.x * w3; acc1.y += v3.y * w3;
        }
        // uniform remainder: both halves run iters times; k may reach nw (<64),
        // where lane nw holds the (0,0) pad -> contributes exactly 0.
        int rem = nw - j;
        int iters = (rem + 1) >> 1;
        for (int it = 0; it < iters; ++it) {
            int k = j + 2 * it + half;
            int s0 = __shfl(el.x, k); float w0 = __int_as_float(__shfl(el.y, k));
            float2 v = unpk(hw1u[s0 * 32 + l]);
            acc1.x += v.x * w0; acc1.y += v.y * w0;
        }
    }
    float ax = (acc0.x + acc1.x), ay = (acc0.y + acc1.y);
    ax += __shfl_xor(ax, 32);
    ay += __shfl_xor(ay, 32);
    if (half == 0) {
        float2 b = ((const float2*)b1)[l];
        float vx = ax + b.x, vy = ay + b.y;
        vx = vx > 0.f ? vx : 0.f;
        vy = vy > 0.f ? vy : 0.f;
        ((float2*)h)[node * 32 + l] = make_float2(vx, vy);
    }
}

// ---- GEMM2: hw2 = bf16(h @ W2) (f32 vector ALU, W2 in LDS) ----
__global__ __launch_bounds__(256) void k_gemm2(
    const float* __restrict__ h, const float* __restrict__ W2,
    ushort_t* __restrict__ hw2, int n)
{
    __shared__ float wsm[HID * NC];  // 10 KB
    for (int i = threadIdx.x; i < HID * NC; i += 256) wsm[i] = W2[i];
    __syncthreads();
    int row = blockIdx.x * 256 + threadIdx.x;
    if (row >= n) return;
    const float4* hr = (const float4*)(h + (size_t)row * HID);
    float acc[NC];
#pragma unroll
    for (int c = 0; c < NC; ++c) acc[c] = 0.f;
#pragma unroll 4
    for (int k4 = 0; k4 < HID / 4; ++k4) {
        float4 hv = hr[k4];
        const float* w0 = wsm + (k4 * 4) * NC;
#pragma unroll
        for (int c = 0; c < NC; ++c)
            acc[c] += hv.x * w0[c] + hv.y * w0[c + NC] + hv.z * w0[c + 2 * NC] + hv.w * w0[c + 3 * NC];
    }
    unsigned int* o = (unsigned int*)(hw2 + (size_t)row * NC);
#pragma unroll
    for (int c2 = 0; c2 < NC / 2; ++c2)
        o[c2] = (unsigned int)f2bf(acc[2 * c2]) | ((unsigned int)f2bf(acc[2 * c2 + 1]) << 16);
}

// ---- agg2: one wave per node; 64-edge register window + shfl broadcast; lanes 0..19/half ----
__global__ __launch_bounds__(256) void k_agg2(
    const int* __restrict__ row_start, const int2* __restrict__ ew,
    const float* __restrict__ dinv, const uint_t* __restrict__ hw2u,
    const float* __restrict__ b2, float* __restrict__ out, int n)
{
    int node = blockIdx.x * 4 + (threadIdx.x >> 6);
    if (node >= n) return;
    int lane = threadIdx.x & 63;
    int half = lane >> 5;
    int l = lane & 31;
    int li = l < 20 ? l : 0;  // clamp idle lanes to a valid address
    int rs = row_start[node];
    int re = row_start[node + 1];
    float di = dinv[node];

    float2 acc0 = make_float2(0.f, 0.f), acc1 = make_float2(0.f, 0.f);
    if (half == 0) {
        float2 v = unpk(hw2u[node * 20 + li]);
        float sl = di * di;
        acc0.x = v.x * sl; acc0.y = v.y * sl;
    }
    for (int base = rs; base < re; base += 64) {
        int nw = re - base; if (nw > 64) nw = 64;
        int idx = base + lane;
        int2 el = (idx < re) ? ew[idx] : make_int2(0, 0);  // pad: s=0, w=0
        int j = 0;
        for (; j + 8 <= nw; j += 8) {   // uniform trip count
            int k0 = j + half;
            int s0 = __shfl(el.x, k0);     float w0 = __int_as_float(__shfl(el.y, k0));
            int s1 = __shfl(el.x, k0 + 2); float w1 = __int_as_float(__shfl(el.y, k0 + 2));
            int s2 = __shfl(el.x, k0 + 4); float w2 = __int_as_float(__shfl(el.y, k0 + 4));
            int s3 = __shfl(el.x, k0 + 6); float w3 = __int_as_float(__shfl(el.y, k0 + 6));
            uint_t p0 = hw2u[s0 * 20 + li];
            uint_t p1 = hw2u[s1 * 20 + li];
            uint_t p2 = hw2u[s2 * 20 + li];
            uint_t p3 = hw2u[s3 * 20 + li];
            float2 v0 = unpk(p0), v1 = unpk(p1), v2 = unpk(p2), v3 = unpk(p3);
            acc0.x += v0.x * w0; acc0.y += v0.y * w0;
            acc1.x += v1.x * w1; acc1.y += v1.y * w1;
            acc0.x += v2.x * w2; acc0.y += v2.y * w2;
            acc1.x += v3.x * w3; acc1.y += v3.y * w3;
        }
        int rem = nw - j;
        int iters = (rem + 1) >> 1;   // uniform remainder (see k_agg1)
        for (int it = 0; it < iters; ++it) {
            int k = j + 2 * it + half;
            int s0 = __shfl(el.x, k); float w0 = __int_as_float(__shfl(el.y, k));
            float2 v = unpk(hw2u[s0 * 20 + li]);
            acc1.x += v.x * w0; acc1.y += v.y * w0;
        }
    }
    float ax = (acc0.x + acc1.x), ay = (acc0.y + acc1.y);
    ax += __shfl_xor(ax, 32);
    ay += __shfl_xor(ay, 32);
    if (half == 0 && l < 20) {
        float2 b = ((const float2*)b2)[l];
        ((float2*)out)[node * 20 + l] = make_float2(ax + b.x, ay + b.y);
    }
}

extern "C" void kernel_launch(void* const* d_in, const int* in_sizes, int n_in,
                              void* d_out, int out_size, void* d_ws, size_t ws_size,
                              hipStream_t stream) {
    const float* x  = (const float*)d_in[0];   // f32 [N,128]
    const int* edge = (const int*)d_in[1];     // int32 [2,E]
    const float* W1 = (const float*)d_in[2];   // f32 [128,64]
    const float* b1 = (const float*)d_in[3];   // f32 [64]
    const float* W2 = (const float*)d_in[4];   // f32 [64,40]
    const float* b2 = (const float*)d_in[5];   // f32 [40]
    float* out      = (float*)d_out;           // f32 [N,40]

    const int n = in_sizes[0] / IN_CH;   // 100000
    const int e = in_sizes[1] / 2;       // 1600000
    const int* srcs = edge;
    const int* dsts = edge + e;

    // workspace layout: ~67 MB total
    int*      gcur      = (int*)d_ws;                       // 256
    int*      bbase     = gcur + 256;                       // 256
    int*      row_start = bbase + 256;                      // NPAD (needs n+1)
    float*    dinv      = (float*)(row_start + NPAD);       // NPAD
    uint_t*   tmp       = (uint_t*)(dinv + NPAD);           // NBUK*CAP packed 4B
    int2*     ew        = (int2*)(tmp + (size_t)NBUK * CAP);// NEDGES (src, w) 8B
    ushort_t* Wp        = (ushort_t*)(ew + NEDGES);         // 8192 bf16
    ushort_t* hw1       = Wp + 8192;                        // N*64 bf16
    float*    h         = (float*)(hw1 + (size_t)NNODES * HID); // N*64 f32
    ushort_t* hw2       = (ushort_t*)(h + (size_t)NNODES * HID); // N*40 bf16

    k_ginit<<<1, 256, 0, stream>>>(gcur);
    k_bin0<<<NBIN, 256, 0, stream>>>(srcs, dsts, gcur, tmp, e);
    k_bbase<<<1, 256, 0, stream>>>(gcur, bbase, e);
    k_sort_a<<<NBUK, 256, 0, stream>>>(tmp, gcur, bbase, row_start, dinv, n, e);
    k_sort_b<<<NBUK, 256, 0, stream>>>(tmp, gcur, row_start, dinv, ew, n);

    k_prepw<<<32, 256, 0, stream>>>(W1, Wp);
    k_gemm1<<<(n + 63) / 64, 256, 0, stream>>>(x, Wp, hw1, n);
    k_agg1<<<(n + 3) / 4, 256, 0, stream>>>(row_start, ew, dinv, (const uint_t*)hw1, b1, h, n);
    k_gemm2<<<(n + 255) / 256, 256, 0, stream>>>(h, W2, hw2, n);
    k_agg2<<<(n + 3) / 4, 256, 0, stream>>>(row_start, ew, dinv, (const uint_t*)hw2, b2, out, n);
}